// Round 16
// baseline (13041.673 us; speedup 1.0000x reference)
//
#include <hip/hip_runtime.h>
#include <math.h>

#define NB 64
#define NH 512
#define NV 64
#define NT 200
#define NSTEP 199
#define GBLK 256
#define GTHR 512

#define RLX   __ATOMIC_RELAXED
#define AGENT __HIP_MEMORY_SCOPE_AGENT
#define WGRP  __HIP_MEMORY_SCOPE_WORKGROUP

typedef float f4v __attribute__((ext_vector_type(4)));

// ---------------- threefry / gumbel (verbatim R8) -------------------------
__device__ inline float gumbel_tf(unsigned f){
  const unsigned ksc[3] = {0u, 1u, 0x1BD11BDBu};
  unsigned x0 = 0u + ksc[0];
  unsigned x1 = f  + ksc[1];
  const int R0[4] = {13,15,26,6};
  const int R1[4] = {17,29,16,24};
  #pragma unroll
  for (int i = 0; i < 5; ++i){
    #pragma unroll
    for (int r = 0; r < 4; ++r){
      int rot = (i & 1) ? R1[r] : R0[r];
      x0 += x1;
      x1 = (x1 << rot) | (x1 >> (32 - rot));
      x1 ^= x0;
    }
    x0 += ksc[(i+1)%3];
    x1 += ksc[(i+2)%3] + (unsigned)(i+1);
  }
  unsigned bits = x0 ^ x1;
  float u = __uint_as_float((bits >> 9) | 0x3F800000u) - 1.0f;
  u = fmaxf(u, 1.17549435e-38f);
  return -logf(-logf(u));
}

__device__ inline float sigf(float x){ return 1.0f/(1.0f + expf(-x)); }

// ---------------- single-wave 256-flag poll (verbatim R15) ----------------
__device__ inline void poll256(unsigned* flags, unsigned tgt){
  const int l = threadIdx.x & 63;
  #pragma unroll
  for (int j = 0; j < 4; ++j){
    while (__hip_atomic_load(&flags[(l*4 + j)*16], RLX, AGENT) < tgt){
      __builtin_amdgcn_s_sleep(1);
    }
  }
}
// ---------------- 256-thread all-flag wait (copier use) -------------------
__device__ inline void gwait_all(unsigned* flags, unsigned tgt){
  if (threadIdx.x < 256){
    while (__hip_atomic_load(&flags[threadIdx.x*16], RLX, AGENT) < tgt){
      __builtin_amdgcn_s_sleep(1);
    }
  }
  __syncthreads();
}

// ---------------- block reductions (verbatim R8) ----------------
__device__ inline float blk_red_max(float v, float* scr){
  #pragma unroll
  for (int m = 1; m < 64; m <<= 1) v = fmaxf(v, __shfl_xor(v, m, 64));
  if ((threadIdx.x & 63) == 0) scr[threadIdx.x >> 6] = v;
  __syncthreads();
  float r = scr[0];
  #pragma unroll
  for (int i = 1; i < 8; ++i) r = fmaxf(r, scr[i]);
  __syncthreads();
  return r;
}
__device__ inline float blk_red_sum(float v, float* scr){
  #pragma unroll
  for (int m = 1; m < 64; m <<= 1) v += __shfl_xor(v, m, 64);
  if ((threadIdx.x & 63) == 0) scr[threadIdx.x >> 6] = v;
  __syncthreads();
  float r = 0.f;
  #pragma unroll
  for (int i = 0; i < 8; ++i) r += scr[i];
  __syncthreads();
  return r;
}

// ---------------- precompute kernels (verbatim R8, pointer-parameterized) -
__global__ void k_msum_part(const float* __restrict__ emb, const int* __restrict__ lens,
                            float* __restrict__ part){
  int blk = blockIdx.x, b = blk >> 3, lc = blk & 7;
  int len = lens[b];
  int l0 = lc*64, l1 = len < l0+64 ? len : l0+64;
  for (int h = threadIdx.x; h < 512; h += 256){
    float a = 0.f;
    for (int l = l0; l < l1; ++l) a += emb[(b*512 + l)*512 + h];
    part[blk*512 + h] = a;
  }
}
__global__ void k_msum(const float* __restrict__ part, float* __restrict__ msumT){
  int b = blockIdx.x;
  for (int h = threadIdx.x; h < 512; h += 256){
    float a = 0.f;
    #pragma unroll
    for (int lc = 0; lc < 8; ++lc) a += part[(b*8+lc)*512 + h];
    msumT[h*64 + b] = a;
  }
}
__global__ void k_kv(const float* __restrict__ msumT,
                     const float* __restrict__ kw, const float* __restrict__ kb,
                     const float* __restrict__ vw, const float* __restrict__ vb,
                     float* __restrict__ keysum, float* __restrict__ valsum){
  int which = blockIdx.x >> 7;
  int i = ((blockIdx.x & 127) << 2) + (threadIdx.x >> 6);
  int b = threadIdx.x & 63;
  const float* W = which ? vw : kw;
  float a = 0.f;
  for (int h = 0; h < 512; ++h) a = fmaf(msumT[h*64+b], W[i*512+h], a);
  float bias = which ? vb[i] : kb[i];
  float* out = which ? valsum : keysum;
  out[b*512 + i] = a + 512.0f*bias;
}
__global__ void k_ceT(const float* __restrict__ ce, float* __restrict__ ceT){
  int idx = blockIdx.x*256 + threadIdx.x;
  if (idx < 32768){ int v = idx >> 9, e = idx & 511; ceT[e*64 + v] = ce[v*512 + e]; }
}
__global__ void k_tok(const float* __restrict__ ceT, const float* __restrict__ w_ih,
                      const float* __restrict__ b_ih, const float* __restrict__ b_hh,
                      float* __restrict__ tok){
  int idx = blockIdx.x*256 + threadIdx.x;
  int v = idx & 63, row = idx >> 6;
  float a = 0.f;
  for (int e = 0; e < 512; ++e) a = fmaf(ceT[e*64+v], w_ih[row*1024 + e], a);
  tok[v*2048 + row] = a + b_ih[row] + b_hh[row];
}
__global__ void k_init(const float* __restrict__ valsum, const float* __restrict__ cdn_w,
                       float* __restrict__ cdnT, float* __restrict__ xT,
                       float* __restrict__ out, unsigned* __restrict__ bar){
  int idx = blockIdx.x*256 + threadIdx.x;
  if (idx < 65536){
    int v = idx >> 10, k = idx & 1023;
    cdnT[k*64 + v] = cdn_w[idx];
  } else if (idx < 98304){
    int r = idx - 65536; int j = r >> 6, b = r & 63;
    xT[j*64 + b] = valsum[b*512 + j] * (1.0f/512.0f);
  } else if (idx < 131072){
    xT[idx - 65536] = 0.f;
  } else if (idx < 135168){
    int r = idx - 131072; int b = r >> 6, v = r & 63;
    out[b*12800 + v] = 0.f;
  } else if (idx < 135232){
    int b = idx - 135168;
    out[819200 + b*200] = 0.f;
  } else if (idx < 139584){
    bar[idx - 135232] = 0u;   // flags[4096] + claim[128] + mflag[128]
  }
}

// ---------------- Phase-A pipeline (FP sequence verbatim R8/R15) ----------
// COH=true: sc0 sc1 (IF$-direct, proven). COH=false: sc0 only (L1-bypass,
// XCD-L2-served — mirror path). Values identical; fmaf order identical.
template<bool COH>
__device__ __forceinline__ void pipeA(const float* base, const float (*W)[8],
                                      int kbase, int bg, float acc[8][4]){
#define ISS1(R, JJ) do{ const float* _p = base + (((kbase + (JJ)*4) << 6) | (bg << 2)); \
  if (COH) asm volatile("global_load_dwordx4 %0, %1, off sc0 sc1" : "=v"(R) : "v"(_p)); \
  else     asm volatile("global_load_dwordx4 %0, %1, off sc0"     : "=v"(R) : "v"(_p)); }while(0)
#define ISS8(P, J0) do{ ISS1(P##0,(J0)+0);ISS1(P##1,(J0)+1);ISS1(P##2,(J0)+2);ISS1(P##3,(J0)+3); \
  ISS1(P##4,(J0)+4);ISS1(P##5,(J0)+5);ISS1(P##6,(J0)+6);ISS1(P##7,(J0)+7); }while(0)
#define CMP1(R, JJ) do{ int _k = kbase + (JJ)*4; \
  f4v _wA = *(const f4v*)&W[_k][0]; f4v _wB = *(const f4v*)&W[_k][4]; \
  float _wv[8] = {_wA.x,_wA.y,_wA.z,_wA.w,_wB.x,_wB.y,_wB.z,_wB.w}; \
  float _xv[4] = {R.x,R.y,R.z,R.w}; \
  _Pragma("unroll") for (int _r = 0; _r < 8; ++_r){ \
    _Pragma("unroll") for (int _q = 0; _q < 4; ++_q) \
      acc[_r][_q] = fmaf(_wv[_r], _xv[_q], acc[_r][_q]); } }while(0)
#define CMP8(P, J0) do{ CMP1(P##0,(J0)+0);CMP1(P##1,(J0)+1);CMP1(P##2,(J0)+2);CMP1(P##3,(J0)+3); \
  CMP1(P##4,(J0)+4);CMP1(P##5,(J0)+5);CMP1(P##6,(J0)+6);CMP1(P##7,(J0)+7); }while(0)
#define WAITV(N) do{ asm volatile("s_waitcnt vmcnt(" #N ")" ::: "memory"); \
  __builtin_amdgcn_sched_barrier(0); }while(0)
  f4v A0,A1,A2,A3,A4,A5,A6,A7,B0,B1,B2,B3,B4,B5,B6,B7;
  ISS8(A, 0);
  ISS8(B, 8);
  WAITV(8); CMP8(A, 0);
  ISS8(A, 16);
  WAITV(8); CMP8(B, 8);
  ISS8(B, 24);
  WAITV(8); CMP8(A, 16);
  WAITV(0); CMP8(B, 24);
#undef ISS1
#undef ISS8
#undef CMP1
#undef CMP8
#undef WAITV
}

// ---------------- main persistent loop kernel ----------------
// MODE 1: h-half per-XCD mirror (ctx stays sc0sc1 broadcast).
// MODE 2: full-x per-XCD mirror.
// FP sequence identical to R8/R15 (5x-passing); only load flags/placement of
// scalar waits change. Mirror filled per step by a CAS-elected copier block on
// each XCD (local normal stores -> local L2 = XCD coherence point), gated by
// monotone mflag[xcd]; copier starts only after ALL flags >= t (everyone done
// reading the mirror), so no read/write race on the single-buffered mirror.
template<int MODE>
__global__ __launch_bounds__(GTHR, 2) void k_loop(
    const float* __restrict__ w_ih, const float* __restrict__ w_hh,
    const int* __restrict__ batch_y, const float* __restrict__ tok,
    const float* __restrict__ keysum, const float* __restrict__ valsum,
    const float* __restrict__ cdnT, const float* __restrict__ cdn_b,
    float* __restrict__ xT, float* __restrict__ mir,
    float* __restrict__ out, unsigned* __restrict__ bar){
  __shared__ float W_lds[1024][8];
  __shared__ float red[8][8][64];
  __shared__ float gates_lds[8][64];
  __shared__ float cc_lds[2][64];
  __shared__ float pb_h[512], pb_c[512];
  __shared__ float pb_lp[8][64];
  __shared__ float scr[8];
  __shared__ int done_h, done_c, done_pb;
  __shared__ int swin;

  unsigned* flags = bar;
  unsigned* claim = bar + 4096;
  unsigned* mflag = bar + 4224;

  const int tid = threadIdx.x;
  const int blk = blockIdx.x;
  const bool HASB = (blk < 64);

  unsigned xcc = 0;
  asm("s_getreg_b32 %0, hwreg(HW_REG_XCC_ID)" : "=s"(xcc));
  xcc &= 7u;
  float* mymir = mir + (size_t)xcc * (MODE == 2 ? 65536 : 32768);
  // base so that (kbase<<6) indexing works unchanged for the mirror reads
  const float* mbase = (MODE == 2) ? mymir : (mymir - 32768);

  if (tid == 0){ done_h = 0; done_c = 0; done_pb = 0; swin = 0; }
  for (int idx = tid; idx < 8192; idx += GTHR){
    int k = idx >> 3, r = idx & 7;
    int g = r >> 1, c = r & 1;
    int row = g*512 + blk*2 + c;
    W_lds[k][r] = (k < 512) ? w_ih[row*1024 + 512 + k] : w_hh[row*512 + (k - 512)];
  }
  if (tid < 128) cc_lds[tid >> 6][tid & 63] = 0.0f;
  __syncthreads();

  const int w = tid >> 6, l = tid & 63, kg = l >> 4, bg = l & 15;
  const float SCALE = 22.627416997969522f;

  for (int s = 0; s < NSTEP; ++s){
    const float* xin  = xT + (size_t)(s & 1)*65536;
    float*       xout = xT + (size_t)((s + 1) & 1)*65536;
    const unsigned t1 = (unsigned)(2*s + 1), t2 = (unsigned)(2*s + 2);
    const unsigned tgt_c = (s == 0) ? 0u : (unsigned)(2*s);
    const unsigned tgt_h = (s == 0) ? 0u : (unsigned)(2*s - 1);

    // ---- per-wave input gating (R15 skeleton) ----
    if (w >= 4){
      if (w == 4){
        if (MODE >= 1 && s > 0){
          while (__hip_atomic_load(&mflag[xcc*16], RLX, AGENT) < (unsigned)s)
            __builtin_amdgcn_s_sleep(1);
        } else {
          poll256(flags, tgt_h);
        }
        __hip_atomic_store(&done_h, s + 1, RLX, WGRP);
      } else {
        while (__hip_atomic_load(&done_h, RLX, WGRP) < s + 1) __builtin_amdgcn_s_sleep(1);
      }
    } else {
      if (w == 0){
        if (MODE == 2 && s > 0){
          while (__hip_atomic_load(&mflag[xcc*16], RLX, AGENT) < (unsigned)s)
            __builtin_amdgcn_s_sleep(1);
        } else {
          poll256(flags, tgt_c);
        }
        __hip_atomic_store(&done_c, s + 1, RLX, WGRP);
      } else {
        while (__hip_atomic_load(&done_c, RLX, WGRP) < s + 1) __builtin_amdgcn_s_sleep(1);
      }
    }

    // tok prefetch (verbatim)
    const int rr = tid >> 6, rb = tid & 63;
    int yprev = (s == 0) ? 0 : batch_y[rb*200 + s];
    float tokval = tok[yprev*2048 + (rr >> 1)*512 + blk*2 + (rr & 1)];

    // ---- Phase A ----
    float acc[8][4];
    #pragma unroll
    for (int r = 0; r < 8; ++r)
      #pragma unroll
      for (int q = 0; q < 4; ++q) acc[r][q] = 0.f;

    const int kbase = w*128 + kg;
    const bool use_mir = (s > 0) && (MODE == 2 || (MODE == 1 && w >= 4));
    if (use_mir) pipeA<false>(mbase, W_lds, kbase, bg, acc);
    else         pipeA<true >(xin,   W_lds, kbase, bg, acc);

    #pragma unroll
    for (int r = 0; r < 8; ++r)
      #pragma unroll
      for (int q = 0; q < 4; ++q){
        float v = acc[r][q];
        v += __shfl_xor(v, 16, 64);
        v += __shfl_xor(v, 32, 64);
        acc[r][q] = v;
      }
    if (l < 16){
      #pragma unroll
      for (int r = 0; r < 8; ++r)
        *(float4*)&red[w][r][bg*4] = make_float4(acc[r][0], acc[r][1], acc[r][2], acc[r][3]);
    }
    __syncthreads();
    {
      float g = 0.f;
      #pragma unroll
      for (int ww = 0; ww < 8; ++ww) g += red[ww][rr][rb];
      gates_lds[rr][rb] = g + tokval;
    }
    __syncthreads();
    if (tid < 128){
      int c = tid >> 6, b = tid & 63;
      float ig = gates_lds[0 + c][b];
      float fg = gates_lds[2 + c][b];
      float gg = gates_lds[4 + c][b];
      float og = gates_lds[6 + c][b];
      float cprev = cc_lds[c][b];
      float cnew = sigf(fg)*cprev + sigf(ig)*tanhf(gg);
      float hnew = sigf(og)*tanhf(cnew);
      cc_lds[c][b] = cnew;
      float oldh = __hip_atomic_exchange(&xout[(512 + blk*2 + c)*64 + b], hnew, RLX, AGENT);
      asm volatile("" :: "v"(oldh));
    }

    // ---- barrier-1 arrival ----
    asm volatile("s_waitcnt vmcnt(0)" ::: "memory");
    __syncthreads();
    if (tid == 0){
      unsigned o = __hip_atomic_exchange(&flags[blk*16], HASB ? t1 : t2, RLX, AGENT);
      asm volatile("" :: "v"(o));
    }

    if (HASB){
      if (w == 4){
        poll256(flags, t1);
        __hip_atomic_store(&done_pb, s + 1, RLX, WGRP);
      } else {
        while (__hip_atomic_load(&done_pb, RLX, WGRP) < s + 1) __builtin_amdgcn_s_sleep(1);
      }

      // ---- Phase B (verbatim R8) ----
      int b = blk;
      int jj = tid;
      float h = __hip_atomic_load(&xout[(512 + jj)*64 + b], RLX, AGENT);
      pb_h[jj] = h;
      float sc = (keysum[b*512 + jj] * h) / SCALE;
      float m = blk_red_max(sc, scr);
      float e = expf(sc - m);
      float S = blk_red_sum(e, scr);
      float cx = valsum[b*512 + jj] * (e / S);
      pb_c[jj] = cx;
      float oldc = __hip_atomic_exchange(&xout[jj*64 + b], cx, RLX, AGENT);
      asm volatile("" :: "v"(oldc));
      __syncthreads();
      int kq = tid >> 6, v = tid & 63;
      float part = 0.f;
      for (int k = kq*128; k < kq*128 + 128; ++k){
        float xh = (k < 512) ? pb_h[k] : pb_c[k - 512];
        part = fmaf(cdnT[k*64 + v], xh, part);
      }
      pb_lp[kq][v] = part;
      __syncthreads();
      if (tid < 64){
        int v2 = tid;
        float logit = cdn_b[v2];
        #pragma unroll
        for (int q = 0; q < 8; ++q) logit += pb_lp[q][v2];
        out[b*12800 + (s+1)*64 + v2] = logit;
        float z = gumbel_tf((unsigned)((b*199 + s)*64 + v2)) + logit;
        int idx = v2;
        #pragma unroll
        for (int mm = 1; mm < 64; mm <<= 1){
          float oz = __shfl_xor(z, mm, 64);
          int   oi = __shfl_xor(idx, mm, 64);
          if (oz > z || (oz == z && oi < idx)){ z = oz; idx = oi; }
        }
        if (v2 == 0) out[819200 + b*200 + (s+1)] = (float)idx;
      }

      asm volatile("s_waitcnt vmcnt(0)" ::: "memory");
      __syncthreads();
      if (tid == 0){
        unsigned o = __hip_atomic_exchange(&flags[blk*16], t2, RLX, AGENT);
        asm volatile("" :: "v"(o));
      }
    }

    // ---- per-XCD mirror copier ----
    if (MODE >= 1 && s < NSTEP - 1){
      if (tid == 0){
        unsigned exp = (unsigned)s;
        bool win = __hip_atomic_compare_exchange_strong(&claim[xcc*16], &exp,
                     (unsigned)(s + 1), RLX, RLX, AGENT);
        swin = win ? 1 : 0;
      }
      __syncthreads();
      if (swin){
        // everyone done reading the mirror (flags set post-PhaseA) AND the
        // needed halves of x(s+1) are final (t1: h; t2: h+ctx).
        gwait_all(flags, (MODE == 2) ? t2 : t1);
        const float* src = xout + ((MODE == 2) ? 0 : 32768);
        float*       dst = mymir;
        const int per = (MODE == 2) ? 32 : 16;   // f4 per thread
        f4v buf0,buf1,buf2,buf3,buf4,buf5,buf6,buf7;
        for (int j0 = 0; j0 < per; j0 += 8){
#define CLD(R, J) do{ const float* _sp = src + (size_t)(((j0+(J))*GTHR + tid))*4; \
  asm volatile("global_load_dwordx4 %0, %1, off sc0 sc1" : "=v"(R) : "v"(_sp)); }while(0)
#define CST(R, J) do{ *(f4v*)(dst + (size_t)(((j0+(J))*GTHR + tid))*4) = R; }while(0)
          CLD(buf0,0); CLD(buf1,1); CLD(buf2,2); CLD(buf3,3);
          CLD(buf4,4); CLD(buf5,5); CLD(buf6,6); CLD(buf7,7);
          asm volatile("s_waitcnt vmcnt(0)" ::: "memory");
          CST(buf0,0); CST(buf1,1); CST(buf2,2); CST(buf3,3);
          CST(buf4,4); CST(buf5,5); CST(buf6,6); CST(buf7,7);
#undef CLD
#undef CST
        }
        asm volatile("s_waitcnt vmcnt(0)" ::: "memory");
        __syncthreads();
        if (tid == 0){
          unsigned o = __hip_atomic_exchange(&mflag[xcc*16], (unsigned)(s + 1), RLX, AGENT);
          asm volatile("" :: "v"(o));
        }
      }
    }
  }
}

// ---------------- launcher ----------------
extern "C" void kernel_launch(void* const* d_in, const int* in_sizes, int n_in,
                              void* d_out, int out_size, void* d_ws, size_t ws_size,
                              hipStream_t stream){
  const float* seq     = (const float*)d_in[0];
  const float* key_w   = (const float*)d_in[1];
  const float* key_b   = (const float*)d_in[2];
  const float* value_w = (const float*)d_in[3];
  const float* value_b = (const float*)d_in[4];
  const float* char_e  = (const float*)d_in[5];
  const float* w_ih    = (const float*)d_in[6];
  const float* w_hh    = (const float*)d_in[7];
  const float* b_ih    = (const float*)d_in[8];
  const float* b_hh    = (const float*)d_in[9];
  const float* cdn_w   = (const float*)d_in[10];
  const float* cdn_b   = (const float*)d_in[11];
  const int*   lens    = (const int*)d_in[12];
  const int*   batch_y = (const int*)d_in[13];
  float* out = (float*)d_out;
  float* ws  = (float*)d_ws;

  const size_t wsw = ws_size / sizeof(float);
  const bool M2 = (wsw >= 922112);     // full-x mirror fits?
  const size_t B = M2 ? 524288 : 262144;

  float* mir       = ws;               // mirrors (k_loop only; overlaps precompute scratch)
  float* msum_part = ws;               // [0, 262144) — dead before k_loop
  float* keysum    = ws + B;
  float* valsum    = ws + B + 32768;
  float* tok       = ws + B + 65536;
  float* cdnT      = ws + B + 196608;
  float* xT        = ws + B + 262144;  // 2 x 65536 ping-pong
  unsigned* bar    = (unsigned*)(ws + B + 393216); // flags 4096 + claim 128 + mflag 128
  float* msumT     = M2 ? (ws + 262144) : (ws + B + 397568);
  float* ceT       = M2 ? (ws + 294912) : (ws);    // M1: reuses msum_part region (dead)

  k_msum_part<<<512, 256, 0, stream>>>(seq, lens, msum_part);
  k_msum     <<<64,  256, 0, stream>>>(msum_part, msumT);
  k_kv       <<<256, 256, 0, stream>>>(msumT, key_w, key_b, value_w, value_b, keysum, valsum);
  k_ceT      <<<128, 256, 0, stream>>>(char_e, ceT);
  k_tok      <<<512, 256, 0, stream>>>(ceT, w_ih, b_ih, b_hh, tok);
  k_init     <<<546, 256, 0, stream>>>(valsum, cdn_w, cdnT, xT, out, bar);

  if (M2){
    k_loop<2><<<GBLK, GTHR, 0, stream>>>(w_ih, w_hh, batch_y, tok, keysum, valsum,
                                         cdnT, cdn_b, xT, mir, out, bar);
  } else {
    k_loop<1><<<GBLK, GTHR, 0, stream>>>(w_ih, w_hh, batch_y, tok, keysum, valsum,
                                         cdnT, cdn_b, xT, mir, out, bar);
  }
  (void)in_sizes; (void)n_in; (void)out_size; (void)ws_size;
}

// Round 17
// 4824.567 us; speedup vs baseline: 2.7032x; 2.7032x over previous
//
#include <hip/hip_runtime.h>
#include <math.h>

#define NB 64
#define NH 512
#define NV 64
#define NT 200
#define NSTEP 199
#define GBLK 256
#define GTHR 512

#define RLX   __ATOMIC_RELAXED
#define AGENT __HIP_MEMORY_SCOPE_AGENT
#define WGRP  __HIP_MEMORY_SCOPE_WORKGROUP

typedef float f4v __attribute__((ext_vector_type(4)));

// ---------------- threefry / gumbel (verbatim R8) -------------------------
__device__ inline float gumbel_tf(unsigned f){
  const unsigned ksc[3] = {0u, 1u, 0x1BD11BDBu};
  unsigned x0 = 0u + ksc[0];
  unsigned x1 = f  + ksc[1];
  const int R0[4] = {13,15,26,6};
  const int R1[4] = {17,29,16,24};
  #pragma unroll
  for (int i = 0; i < 5; ++i){
    #pragma unroll
    for (int r = 0; r < 4; ++r){
      int rot = (i & 1) ? R1[r] : R0[r];
      x0 += x1;
      x1 = (x1 << rot) | (x1 >> (32 - rot));
      x1 ^= x0;
    }
    x0 += ksc[(i+1)%3];
    x1 += ksc[(i+2)%3] + (unsigned)(i+1);
  }
  unsigned bits = x0 ^ x1;
  float u = __uint_as_float((bits >> 9) | 0x3F800000u) - 1.0f;
  u = fmaxf(u, 1.17549435e-38f);
  return -logf(-logf(u));
}

__device__ inline float sigf(float x){ return 1.0f/(1.0f + expf(-x)); }

// ---------------- flag polls ----------------
// all 256 flags (one wave: 64 lanes x 4)
__device__ inline void poll256(unsigned* flags, unsigned tgt){
  const int l = threadIdx.x & 63;
  #pragma unroll
  for (int j = 0; j < 4; ++j){
    while (__hip_atomic_load(&flags[(l*4 + j)*16], RLX, AGENT) < tgt){
      __builtin_amdgcn_s_sleep(1);
    }
  }
}
// B-block flags only (0..63), one lane each
__device__ inline void poll64(unsigned* flags, unsigned tgt){
  const int l = threadIdx.x & 63;
  while (__hip_atomic_load(&flags[l*16], RLX, AGENT) < tgt){
    __builtin_amdgcn_s_sleep(1);
  }
}

// ---------------- block reductions (verbatim R8) ----------------
__device__ inline float blk_red_max(float v, float* scr){
  #pragma unroll
  for (int m = 1; m < 64; m <<= 1) v = fmaxf(v, __shfl_xor(v, m, 64));
  if ((threadIdx.x & 63) == 0) scr[threadIdx.x >> 6] = v;
  __syncthreads();
  float r = scr[0];
  #pragma unroll
  for (int i = 1; i < 8; ++i) r = fmaxf(r, scr[i]);
  __syncthreads();
  return r;
}
__device__ inline float blk_red_sum(float v, float* scr){
  #pragma unroll
  for (int m = 1; m < 64; m <<= 1) v += __shfl_xor(v, m, 64);
  if ((threadIdx.x & 63) == 0) scr[threadIdx.x >> 6] = v;
  __syncthreads();
  float r = 0.f;
  #pragma unroll
  for (int i = 0; i < 8; ++i) r += scr[i];
  __syncthreads();
  return r;
}

// ---------------- precompute kernels (verbatim R8) -----------
__global__ void k_msum_part(const float* __restrict__ emb, const int* __restrict__ lens,
                            float* __restrict__ part){
  int blk = blockIdx.x, b = blk >> 3, lc = blk & 7;
  int len = lens[b];
  int l0 = lc*64, l1 = len < l0+64 ? len : l0+64;
  for (int h = threadIdx.x; h < 512; h += 256){
    float a = 0.f;
    for (int l = l0; l < l1; ++l) a += emb[(b*512 + l)*512 + h];
    part[blk*512 + h] = a;
  }
}
__global__ void k_msum(const float* __restrict__ part, float* __restrict__ msumT){
  int b = blockIdx.x;
  for (int h = threadIdx.x; h < 512; h += 256){
    float a = 0.f;
    #pragma unroll
    for (int lc = 0; lc < 8; ++lc) a += part[(b*8+lc)*512 + h];
    msumT[h*64 + b] = a;
  }
}
__global__ void k_kv(const float* __restrict__ msumT,
                     const float* __restrict__ kw, const float* __restrict__ kb,
                     const float* __restrict__ vw, const float* __restrict__ vb,
                     float* __restrict__ keysum, float* __restrict__ valsum){
  int which = blockIdx.x >> 7;
  int i = ((blockIdx.x & 127) << 2) + (threadIdx.x >> 6);
  int b = threadIdx.x & 63;
  const float* W = which ? vw : kw;
  float a = 0.f;
  for (int h = 0; h < 512; ++h) a = fmaf(msumT[h*64+b], W[i*512+h], a);
  float bias = which ? vb[i] : kb[i];
  float* out = which ? valsum : keysum;
  out[b*512 + i] = a + 512.0f*bias;
}
__global__ void k_ceT(const float* __restrict__ ce, float* __restrict__ ceT){
  int idx = blockIdx.x*256 + threadIdx.x;
  if (idx < 32768){ int v = idx >> 9, e = idx & 511; ceT[e*64 + v] = ce[v*512 + e]; }
}
__global__ void k_tok(const float* __restrict__ ceT, const float* __restrict__ w_ih,
                      const float* __restrict__ b_ih, const float* __restrict__ b_hh,
                      float* __restrict__ tok){
  int idx = blockIdx.x*256 + threadIdx.x;
  int v = idx & 63, row = idx >> 6;
  float a = 0.f;
  for (int e = 0; e < 512; ++e) a = fmaf(ceT[e*64+v], w_ih[row*1024 + e], a);
  tok[v*2048 + row] = a + b_ih[row] + b_hh[row];
}
__global__ void k_init(const float* __restrict__ valsum, const float* __restrict__ cdn_w,
                       float* __restrict__ cdnT, float* __restrict__ xT,
                       float* __restrict__ out, unsigned* __restrict__ bar){
  int idx = blockIdx.x*256 + threadIdx.x;
  if (idx < 65536){
    int v = idx >> 10, k = idx & 1023;
    cdnT[k*64 + v] = cdn_w[idx];
  } else if (idx < 98304){
    int r = idx - 65536; int j = r >> 6, b = r & 63;
    xT[j*64 + b] = valsum[b*512 + j] * (1.0f/512.0f);
  } else if (idx < 131072){
    xT[idx - 65536] = 0.f;
  } else if (idx < 135168){
    int r = idx - 131072; int b = r >> 6, v = r & 63;
    out[b*12800 + v] = 0.f;
  } else if (idx < 135232){
    int b = idx - 135168;
    out[819200 + b*200] = 0.f;
  } else if (idx < 139328){
    bar[idx - 135232] = 0u;   // flags[256*16]
  }
}

// ---------------- main persistent loop kernel ----------------
// R8 FP sequence byte-preserved. Structural changes only:
//  - blocks 0-63  (B): Phase B = gather h (coalesced from hT) -> softmax ->
//    ctx writes (xout + transposed ctxT) -> t2. No logits/sampling.
//  - blocks 64-127 (L): compute logits+sampling for step s-1 after their
//    barrier-1 arrival (pipelined; gates nothing). Buffers: hT triple-buffered,
//    ctxT double-buffered; rotation proven race-free by the flag protocol.
//  - waves 0-3 ctx gate polls only the 64 B-flags (ctx written only by B).
__global__ __launch_bounds__(GTHR, 2) void k_loop(
    const float* __restrict__ w_ih, const float* __restrict__ w_hh,
    const int* __restrict__ batch_y, const float* __restrict__ tok,
    const float* __restrict__ keysum, const float* __restrict__ valsum,
    const float* __restrict__ cdnT, const float* __restrict__ cdn_b,
    float* __restrict__ xT, float* __restrict__ hT3, float* __restrict__ ctxT,
    float* __restrict__ out, unsigned* __restrict__ flags){
  __shared__ float W_lds[1024][8];
  __shared__ float red[8][8][64];
  __shared__ float gates_lds[8][64];
  __shared__ float cc_lds[2][64];
  __shared__ float pb_h[512], pb_c[512];
  __shared__ float pb_lp[8][64];
  __shared__ float scr[8];
  __shared__ int done_h, done_c, done_pb;

  const int tid = threadIdx.x;
  const int blk = blockIdx.x;
  const bool HASB = (blk < 64);
  const bool HASL = (blk >= 64 && blk < 128);

  if (tid == 0){ done_h = 0; done_c = 0; done_pb = 0; }
  for (int idx = tid; idx < 8192; idx += GTHR){
    int k = idx >> 3, r = idx & 7;
    int g = r >> 1, c = r & 1;
    int row = g*512 + blk*2 + c;
    W_lds[k][r] = (k < 512) ? w_ih[row*1024 + 512 + k] : w_hh[row*512 + (k - 512)];
  }
  if (tid < 128) cc_lds[tid >> 6][tid & 63] = 0.0f;
  __syncthreads();

  const int w = tid >> 6, l = tid & 63, kg = l >> 4, bg = l & 15;
  const float SCALE = 22.627416997969522f;

#define ISS1(R, JJ) do{ const float* _p = xin + (((kbase + (JJ)*4) << 6) | (bg << 2)); \
  asm volatile("global_load_dwordx4 %0, %1, off sc0 sc1" : "=v"(R) : "v"(_p)); }while(0)
#define ISS8(P, J0) do{ ISS1(P##0,(J0)+0);ISS1(P##1,(J0)+1);ISS1(P##2,(J0)+2);ISS1(P##3,(J0)+3); \
  ISS1(P##4,(J0)+4);ISS1(P##5,(J0)+5);ISS1(P##6,(J0)+6);ISS1(P##7,(J0)+7); }while(0)
#define CMP1(R, JJ) do{ int _k = kbase + (JJ)*4; \
  f4v _wA = *(const f4v*)&W_lds[_k][0]; f4v _wB = *(const f4v*)&W_lds[_k][4]; \
  float _wv[8] = {_wA.x,_wA.y,_wA.z,_wA.w,_wB.x,_wB.y,_wB.z,_wB.w}; \
  float _xv[4] = {R.x,R.y,R.z,R.w}; \
  _Pragma("unroll") for (int _r = 0; _r < 8; ++_r){ \
    _Pragma("unroll") for (int _q = 0; _q < 4; ++_q) \
      acc[_r][_q] = fmaf(_wv[_r], _xv[_q], acc[_r][_q]); } }while(0)
#define CMP8(P, J0) do{ CMP1(P##0,(J0)+0);CMP1(P##1,(J0)+1);CMP1(P##2,(J0)+2);CMP1(P##3,(J0)+3); \
  CMP1(P##4,(J0)+4);CMP1(P##5,(J0)+5);CMP1(P##6,(J0)+6);CMP1(P##7,(J0)+7); }while(0)
#define WAITV(N) do{ asm volatile("s_waitcnt vmcnt(" #N ")" ::: "memory"); \
  __builtin_amdgcn_sched_barrier(0); }while(0)

  for (int s = 0; s < NSTEP; ++s){
    const float* xin  = xT + (size_t)(s & 1)*65536;
    float*       xout = xT + (size_t)((s + 1) & 1)*65536;
    const unsigned t1 = (unsigned)(2*s + 1), t2 = (unsigned)(2*s + 2);
    const unsigned tgt_h = (s == 0) ? 0u : (unsigned)(2*s - 1);
    const unsigned tgt_c = (s == 0) ? 0u : (unsigned)(2*s);

    // ---- per-wave input gating (R15 skeleton; ctx gate narrowed to 64 flags) ----
    if (w >= 4){
      if (w == 4){
        poll256(flags, tgt_h);
        __hip_atomic_store(&done_h, s + 1, RLX, WGRP);
      } else {
        while (__hip_atomic_load(&done_h, RLX, WGRP) < s + 1) __builtin_amdgcn_s_sleep(1);
      }
    } else {
      if (w == 0){
        poll64(flags, tgt_c);
        __hip_atomic_store(&done_c, s + 1, RLX, WGRP);
      } else {
        while (__hip_atomic_load(&done_c, RLX, WGRP) < s + 1) __builtin_amdgcn_s_sleep(1);
      }
    }

    // tok prefetch (verbatim R8)
    const int rr = tid >> 6, rb = tid & 63;
    int yprev = (s == 0) ? 0 : batch_y[rb*200 + s];
    float tokval = tok[yprev*2048 + (rr >> 1)*512 + blk*2 + (rr & 1)];

    // ---- Phase A (verbatim R8) ----
    float acc[8][4];
    #pragma unroll
    for (int r = 0; r < 8; ++r)
      #pragma unroll
      for (int q = 0; q < 4; ++q) acc[r][q] = 0.f;

    const int kbase = w*128 + kg;
    {
      f4v A0,A1,A2,A3,A4,A5,A6,A7,B0,B1,B2,B3,B4,B5,B6,B7;
      ISS8(A, 0);
      ISS8(B, 8);
      WAITV(8); CMP8(A, 0);
      ISS8(A, 16);
      WAITV(8); CMP8(B, 8);
      ISS8(B, 24);
      WAITV(8); CMP8(A, 16);
      WAITV(0); CMP8(B, 24);
    }

    #pragma unroll
    for (int r = 0; r < 8; ++r)
      #pragma unroll
      for (int q = 0; q < 4; ++q){
        float v = acc[r][q];
        v += __shfl_xor(v, 16, 64);
        v += __shfl_xor(v, 32, 64);
        acc[r][q] = v;
      }
    if (l < 16){
      #pragma unroll
      for (int r = 0; r < 8; ++r)
        *(float4*)&red[w][r][bg*4] = make_float4(acc[r][0], acc[r][1], acc[r][2], acc[r][3]);
    }
    __syncthreads();
    {
      float g = 0.f;
      #pragma unroll
      for (int ww = 0; ww < 8; ++ww) g += red[ww][rr][rb];
      gates_lds[rr][rb] = g + tokval;
    }
    __syncthreads();
    if (tid < 128){
      int c = tid >> 6, b = tid & 63;
      float ig = gates_lds[0 + c][b];
      float fg = gates_lds[2 + c][b];
      float gg = gates_lds[4 + c][b];
      float og = gates_lds[6 + c][b];
      float cprev = cc_lds[c][b];
      float cnew = sigf(fg)*cprev + sigf(ig)*tanhf(gg);
      float hnew = sigf(og)*tanhf(cnew);
      cc_lds[c][b] = cnew;
      float oldh = __hip_atomic_exchange(&xout[(512 + blk*2 + c)*64 + b], hnew, RLX, AGENT);
      asm volatile("" :: "v"(oldh));
      // transposed copy for coalesced gathers (same bits)
      float oldt = __hip_atomic_exchange(
          &hT3[(size_t)((s + 1) % 3)*32768 + b*512 + (blk*2 + c)], hnew, RLX, AGENT);
      asm volatile("" :: "v"(oldt));
    }

    // ---- barrier-1 arrival ----
    asm volatile("s_waitcnt vmcnt(0)" ::: "memory");
    __syncthreads();
    if (tid == 0){
      unsigned o = __hip_atomic_exchange(&flags[blk*16], HASB ? t1 : t2, RLX, AGENT);
      asm volatile("" :: "v"(o));
    }

    if (HASB){
      if (w == 4){
        poll256(flags, t1);
        __hip_atomic_store(&done_pb, s + 1, RLX, WGRP);
      } else {
        while (__hip_atomic_load(&done_pb, RLX, WGRP) < s + 1) __builtin_amdgcn_s_sleep(1);
      }

      // ---- Phase B core (softmax + ctx only; FP verbatim R8) ----
      int b = blk;
      int jj = tid;
      float h;
      { const float* hp = hT3 + (size_t)((s + 1) % 3)*32768 + b*512 + jj;
        asm volatile("global_load_dword %0, %1, off sc0 sc1" : "=v"(h) : "v"(hp));
        asm volatile("s_waitcnt vmcnt(0)" ::: "memory"); }
      pb_h[jj] = h;
      float sc = (keysum[b*512 + jj] * h) / SCALE;
      float m = blk_red_max(sc, scr);
      float e = expf(sc - m);
      float S = blk_red_sum(e, scr);
      float cx = valsum[b*512 + jj] * (e / S);
      float oldc = __hip_atomic_exchange(&xout[jj*64 + b], cx, RLX, AGENT);
      asm volatile("" :: "v"(oldc));
      float oldt = __hip_atomic_exchange(&ctxT[(size_t)(s & 1)*32768 + b*512 + jj], cx, RLX, AGENT);
      asm volatile("" :: "v"(oldt));
      asm volatile("s_waitcnt vmcnt(0)" ::: "memory");
      __syncthreads();
      if (tid == 0){
        unsigned o = __hip_atomic_exchange(&flags[blk*16], t2, RLX, AGENT);
        asm volatile("" :: "v"(o));
      }
    }

    if (HASL && s >= 1){
      // ---- pipelined logits + sampling for step sp = s-1 (off critical path).
      // Inputs ready: hT3[s%3] (h(sp+1), gated via this step's t1(s-1)>=2s-1 poll)
      // and ctxT[(s-1)&1] (gated via this step's poll64 >= 2s = t2(s-1)).
      int b = blk - 64;
      int sp = s - 1;
      float h, c;
      { const float* hp = hT3 + (size_t)(s % 3)*32768 + b*512 + tid;
        const float* cp = ctxT + (size_t)(sp & 1)*32768 + b*512 + tid;
        asm volatile("global_load_dword %0, %1, off sc0 sc1" : "=v"(h) : "v"(hp));
        asm volatile("global_load_dword %0, %1, off sc0 sc1" : "=v"(c) : "v"(cp));
        asm volatile("s_waitcnt vmcnt(0)" ::: "memory"); }
      pb_h[tid] = h;
      pb_c[tid] = c;
      __syncthreads();
      int kq = tid >> 6, v = tid & 63;
      float part = 0.f;
      for (int k = kq*128; k < kq*128 + 128; ++k){
        float xh = (k < 512) ? pb_h[k] : pb_c[k - 512];
        part = fmaf(cdnT[k*64 + v], xh, part);
      }
      pb_lp[kq][v] = part;
      __syncthreads();
      if (tid < 64){
        int v2 = tid;
        float logit = cdn_b[v2];
        #pragma unroll
        for (int q = 0; q < 8; ++q) logit += pb_lp[q][v2];
        out[b*12800 + (sp+1)*64 + v2] = logit;
        float z = gumbel_tf((unsigned)((b*199 + sp)*64 + v2)) + logit;
        int idx = v2;
        #pragma unroll
        for (int mm = 1; mm < 64; mm <<= 1){
          float oz = __shfl_xor(z, mm, 64);
          int   oi = __shfl_xor(idx, mm, 64);
          if (oz > z || (oz == z && oi < idx)){ z = oz; idx = oi; }
        }
        if (v2 == 0) out[819200 + b*200 + (sp+1)] = (float)idx;
      }
    }
  }

  // ---- epilogue: logits/sampling for sp = NSTEP-1 = 198 (L-blocks) ----
  if (HASL){
    int b = blk - 64;
    const int sp = NSTEP - 1;                      // 198
    if (tid == 0){
      while (__hip_atomic_load(&flags[b*16], RLX, AGENT) < (unsigned)(2*sp + 2))
        __builtin_amdgcn_s_sleep(1);
    }
    __syncthreads();
    float h, c;
    { const float* hp = hT3 + (size_t)((sp + 1) % 3)*32768 + b*512 + tid;
      const float* cp = ctxT + (size_t)(sp & 1)*32768 + b*512 + tid;
      asm volatile("global_load_dword %0, %1, off sc0 sc1" : "=v"(h) : "v"(hp));
      asm volatile("global_load_dword %0, %1, off sc0 sc1" : "=v"(c) : "v"(cp));
      asm volatile("s_waitcnt vmcnt(0)" ::: "memory"); }
    pb_h[tid] = h;
    pb_c[tid] = c;
    __syncthreads();
    int kq = tid >> 6, v = tid & 63;
    float part = 0.f;
    for (int k = kq*128; k < kq*128 + 128; ++k){
      float xh = (k < 512) ? pb_h[k] : pb_c[k - 512];
      part = fmaf(cdnT[k*64 + v], xh, part);
    }
    pb_lp[kq][v] = part;
    __syncthreads();
    if (tid < 64){
      int v2 = tid;
      float logit = cdn_b[v2];
      #pragma unroll
      for (int q = 0; q < 8; ++q) logit += pb_lp[q][v2];
      out[b*12800 + (sp+1)*64 + v2] = logit;
      float z = gumbel_tf((unsigned)((b*199 + sp)*64 + v2)) + logit;
      int idx = v2;
      #pragma unroll
      for (int mm = 1; mm < 64; mm <<= 1){
        float oz = __shfl_xor(z, mm, 64);
        int   oi = __shfl_xor(idx, mm, 64);
        if (oz > z || (oz == z && oi < idx)){ z = oz; idx = oi; }
      }
      if (v2 == 0) out[819200 + b*200 + (sp+1)] = (float)idx;
    }
  }
#undef ISS1
#undef ISS8
#undef CMP1
#undef CMP8
#undef WAITV
}

// ---------------- launcher ----------------
extern "C" void kernel_launch(void* const* d_in, const int* in_sizes, int n_in,
                              void* d_out, int out_size, void* d_ws, size_t ws_size,
                              hipStream_t stream){
  const float* seq     = (const float*)d_in[0];
  const float* key_w   = (const float*)d_in[1];
  const float* key_b   = (const float*)d_in[2];
  const float* value_w = (const float*)d_in[3];
  const float* value_b = (const float*)d_in[4];
  const float* char_e  = (const float*)d_in[5];
  const float* w_ih    = (const float*)d_in[6];
  const float* w_hh    = (const float*)d_in[7];
  const float* b_ih    = (const float*)d_in[8];
  const float* b_hh    = (const float*)d_in[9];
  const float* cdn_w   = (const float*)d_in[10];
  const float* cdn_b   = (const float*)d_in[11];
  const int*   lens    = (const int*)d_in[12];
  const int*   batch_y = (const int*)d_in[13];
  float* out = (float*)d_out;
  float* ws  = (float*)d_ws;

  // R8-proven footprint. hT3/ctxT overlay the msum_part scratch (dead after
  // k_msum; k_loop writes each slot before any gated read).
  float* hT3       = ws;              // 3 x 32768  [b][row] transposed h
  float* ctxT      = ws + 98304;      // 2 x 32768  [b][row] transposed ctx
  float* msum_part = ws;              // 262144 (precompute only)
  float* msumT     = ws + 262144;     // 32768
  float* keysum    = ws + 294912;     // 32768
  float* valsum    = ws + 327680;     // 32768
  float* tok       = ws + 360448;     // 131072
  float* cdnT      = ws + 491520;     // 65536
  float* ceT       = ws + 557056;     // 32768
  float* xT        = ws + 589824;     // 2 x 65536 ping-pong
  unsigned* bar    = (unsigned*)(ws + 720896); // flags[256*16]

  k_msum_part<<<512, 256, 0, stream>>>(seq, lens, msum_part);
  k_msum     <<<64,  256, 0, stream>>>(msum_part, msumT);
  k_kv       <<<256, 256, 0, stream>>>(msumT, key_w, key_b, value_w, value_b, keysum, valsum);
  k_ceT      <<<128, 256, 0, stream>>>(char_e, ceT);
  k_tok      <<<512, 256, 0, stream>>>(ceT, w_ih, b_ih, b_hh, tok);
  k_init     <<<545, 256, 0, stream>>>(valsum, cdn_w, cdnT, xT, out, bar);

  k_loop<<<GBLK, GTHR, 0, stream>>>(w_ih, w_hh, batch_y, tok, keysum, valsum,
                                    cdnT, cdn_b, xT, hT3, ctxT, out, bar);
  (void)in_sizes; (void)n_in; (void)out_size; (void)ws_size;
}